// Round 1
// baseline (267.830 us; speedup 1.0000x reference)
//
#include <hip/hip_runtime.h>
#include <float.h>

typedef _Float16 half8  __attribute__((ext_vector_type(8)));
typedef __fp16   fp16x2 __attribute__((ext_vector_type(2)));
typedef float    f32x16 __attribute__((ext_vector_type(16)));

#define NTOK  65536
#define DIM   256
#define NCODE 1024
#define TT    64          // tokens per block (was 128); grid = 1024 -> 4 blocks/CU
#define NCT   16          // 16 code-tiles of 64 codes
#define CAP   4096
#define TAU   0.08f
#define BIAS  64.0f       // coarse scores strictly positive -> uint order == float order

__device__ inline half8 pack8(float4 a, float4 b) {
    union { half8 v; fp16x2 h[4]; } u;
    u.h[0] = __builtin_amdgcn_cvt_pkrtz(a.x, a.y);
    u.h[1] = __builtin_amdgcn_cvt_pkrtz(a.z, a.w);
    u.h[2] = __builtin_amdgcn_cvt_pkrtz(b.x, b.y);
    u.h[3] = __builtin_amdgcn_cvt_pkrtz(b.z, b.w);
    return u.v;
}
__device__ inline unsigned umn(unsigned a, unsigned b) { return a < b ? a : b; }
__device__ inline unsigned umx(unsigned a, unsigned b) { return a > b ? a : b; }

// async 16B global->LDS; LDS dest is wave-uniform base + lane*16 by construction
__device__ inline void gload16(const void* g, void* l) {
    __builtin_amdgcn_global_load_lds(
        (__attribute__((address_space(1))) void*)(size_t)g,
        (__attribute__((address_space(3))) void*)l,
        16, 0, 0);
}

// pre-kernel: ||W_k||^2 (fp64->fp32) + W -> f16 chunks (row-major half8)
// 32 lanes per code, 8 codes per block -> grid 128 (was 4 blocks / 1024 threads)
__global__ __launch_bounds__(256) void prep_kernel(const float* __restrict__ W,
                                                   float* __restrict__ nw_out,
                                                   half8* __restrict__ wh_out) {
    const int tid = threadIdx.x;
    const int k = blockIdx.x * 8 + (tid >> 5);
    const int c = tid & 31;
    const float4* wr = (const float4*)(W + (size_t)k * DIM + c * 8);
    float4 u = wr[0], v = wr[1];
    wh_out[(size_t)k * 32 + c] = pack8(u, v);
    double a = (double)u.x * u.x + (double)u.y * u.y + (double)u.z * u.z + (double)u.w * u.w
             + (double)v.x * v.x + (double)v.y * v.y + (double)v.z * v.z + (double)v.w * v.w;
    #pragma unroll
    for (int m = 1; m <= 16; m <<= 1) a += __shfl_xor(a, m);   // stays within 32-lane group
    if (c == 0) nw_out[k] = (float)a;
}

template <bool PRE>
__global__ __launch_bounds__(256, 4) void vq_kernel(
    const float* __restrict__ x, const float* __restrict__ W,
    const float* __restrict__ nwp, const half8* __restrict__ whp,
    float* __restrict__ outq, float* __restrict__ outidx)
{
    __shared__ _Float16 wtile[64][256];        // 32 KB; aliased as cand list after loop
    __shared__ float nw_s[NCODE];              // 4 KB
    __shared__ float nx_s[TT];
    __shared__ unsigned long long best64[TT];
    __shared__ int cnt_s;
    __shared__ int bk_s[TT];
    unsigned* cand = (unsigned*)&wtile[0][0];

    const int tid = threadIdx.x, tb = blockIdx.x * TT;
    const int wv = tid >> 6, l = tid & 63, h = l >> 5, ln = l & 31;
    const int tg = wv & 1;      // token group (2 x 32 tokens)
    const int ch = wv >> 1;     // code half of each 64-code tile

    // ---- nw: load precomputed, or fp64 in-block fallback ----
    if (PRE) {
        ((float4*)nw_s)[tid] = ((const float4*)nwp)[tid];
    } else {
        #pragma unroll
        for (int c = 0; c < 4; ++c) {
            const int k = (tid << 2) + c;
            const float4* wr = (const float4*)(W + (size_t)k * DIM);
            double a0 = 0.0, a1 = 0.0;
            for (int q = 0; q < DIM / 4; ++q) {
                float4 v = wr[q];
                a0 += (double)v.x * v.x + (double)v.y * v.y;
                a1 += (double)v.z * v.z + (double)v.w * v.w;
            }
            nw_s[k] = (float)(a0 + a1);
        }
    }
    if (tid == 0) cnt_s = 0;
    if (tid < TT) best64[tid] = ~0ull;

    // ---- A-fragments in registers + FUSED fp64 token norms (no separate x pass) ----
    const int trow = tb + (tg << 5) + ln;
    half8 xa[16];
    double a0 = 0.0, a1 = 0.0;
    #pragma unroll
    for (int s = 0; s < 16; ++s) {
        const float4* p = (const float4*)(x + (size_t)trow * DIM + (s << 4) + (h << 3));
        float4 u = p[0], v = p[1];
        xa[s] = pack8(u, v);
        if (ch == 0) {   // wave-uniform; only one wave pair computes norms
            a0 += (double)u.x * u.x + (double)u.y * u.y + (double)v.x * v.x + (double)v.y * v.y;
            a1 += (double)u.z * u.z + (double)u.w * u.w + (double)v.z * v.z + (double)v.w * v.w;
        }
    }
    if (ch == 0) {
        double nx = a0 + a1;
        nx += __shfl_xor(nx, 32);               // combine the two dim-halves (h=0 / h=1)
        if (h == 0) nx_s[(tg << 5) + ln] = (float)nx;
    }

    // per-lane top-2 packed keys per C-reg slot (16 slots x 2 rows-per-h = 32 rows)
    unsigned b0[16], b1[16];
    #pragma unroll
    for (int e = 0; e < 16; ++e) { b0[e] = 0xFFFFFFFFu; b1[e] = 0xFFFFFFFFu; }

    for (int ct = 0; ct < NCT; ++ct) {
        __syncthreads();   // prior MFMA readers of wtile done
        if (PRE) {
            // async direct-to-LDS staging; swizzle applied on the GLOBAL index so the
            // LDS destination stays linear (base + lane*16). Linear slot g holds
            // chunk (g&31)^((g>>5)&31) of tile-row g>>5.
            #pragma unroll
            for (int j = 0; j < 8; ++j) {
                const int g = j * 256 + tid;
                const int src = (g & ~31) | ((g & 31) ^ ((g >> 5) & 31));
                gload16(whp + (size_t)ct * 2048 + src, (_Float16*)&wtile[0][0] + (size_t)g * 8);
            }
        } else {
            const int n = tid >> 2, qq = tid & 3;
            const float4* srcp = (const float4*)(W + (size_t)(ct * 64 + n) * DIM + (qq << 6));
            #pragma unroll
            for (int i = 0; i < 8; ++i) {
                float4 a = srcp[2 * i], b = srcp[2 * i + 1];
                const int c = (qq << 3) + i, p = c ^ (n & 31);
                *(half8*)&wtile[n][p << 3] = pack8(a, b);
            }
        }
        __syncthreads();   // drains vmcnt (global_load_lds) / lgkmcnt

        f32x16 acc;
        #pragma unroll
        for (int e = 0; e < 16; ++e) acc[e] = 0.0f;

        #pragma unroll
        for (int sp = 0; sp < 16; ++sp) {
            const int p = ((sp << 1) + h) ^ ln;                     // XOR-deswizzle
            half8 q = *(const half8*)&wtile[(ch << 5) + ln][p << 3];
            acc = __builtin_amdgcn_mfma_f32_32x32x16_f16(xa[sp], q, acc, 0, 0, 0);
        }

        // ---- branch-free register top-2 on packed (score,k) keys ----
        const int kk = (ct << 6) + (ch << 5) + ln;
        const float nwb = nw_s[kk] + BIAS;
        #pragma unroll
        for (int e = 0; e < 16; ++e) {
            const float c = fmaf(acc[e], -2.0f, nwb);
            const unsigned u = (__float_as_uint(c) & 0xFFFFFC00u) | (unsigned)kk;
            const unsigned lo = umn(u, b0[e]), hi = umx(u, b0[e]);
            b0[e] = lo;
            b1[e] = umn(hi, b1[e]);
        }
    }

    __syncthreads();   // all MFMA reads of wtile done; alias as cand list

    // ---- per-row cross-lane coarse min (32 lanes, same h), tau-trigger, append ----
    // each wave covers its 512-code half; per-wave thresholds >= global threshold,
    // so the union of appended candidates is a superset of the needed set.
    #pragma unroll
    for (int e = 0; e < 16; ++e) {
        unsigned v = b0[e];
        #pragma unroll
        for (int m = 1; m <= 16; m <<= 1) v = umn(v, (unsigned)__shfl_xor((int)v, m));
        const float thr = __uint_as_float(v & 0xFFFFFC00u) + TAU;
        const int t = (tg << 5) + (e & 3) + ((e >> 2) << 3) + (h << 2);
        if (__uint_as_float(b0[e] & 0xFFFFFC00u) <= thr) {
            int i = atomicAdd(&cnt_s, 1);
            if (i < CAP) cand[i] = ((unsigned)t << 10) | (b0[e] & 1023u);
        }
        if (__uint_as_float(b1[e] & 0xFFFFFC00u) <= thr) {
            int i = atomicAdd(&cnt_s, 1);
            if (i < CAP) cand[i] = ((unsigned)t << 10) | (b1[e] & 1023u);
        }
    }
    __syncthreads();

    // ---- wave-cooperative exact fp32 rescore; lexicographic (dv,k) atomicMin ----
    // (kept bit-identical to the passing kernel's reduction shape)
    const int nc = min(cnt_s, CAP);
    for (int c = wv; c < nc; c += 4) {
        const unsigned en = cand[c];
        const int t = en >> 10, k = en & 1023;
        float4 xv = ((const float4*)(x + (size_t)(tb + t) * DIM))[l];
        float4 wr = ((const float4*)(W + (size_t)k * DIM))[l];
        float s = fmaf(xv.x, wr.x, fmaf(xv.y, wr.y, fmaf(xv.z, wr.z, xv.w * wr.w)));
        #pragma unroll
        for (int m = 1; m <= 32; m <<= 1) s += __shfl_xor(s, m);
        const float dv = (nx_s[t] + nw_s[k]) - 2.0f * s;
        if (l == 0) {
            unsigned long long key = ((unsigned long long)__float_as_uint(dv) << 32) | (unsigned)k;
            atomicMin(&best64[t], key);
        }
    }
    __syncthreads();

    if (tid < TT) {
        const int bk = (int)(best64[tid] & 1023u);
        bk_s[tid] = bk;
        outidx[tb + tid] = (float)bk;
    }
    __syncthreads();

    // ---- gather codebook rows -> quantized output (coalesced float4) ----
    for (int i = tid; i < TT * (DIM / 4); i += 256) {
        const int t = i >> 6, j = i & 63;
        const float4* wr = (const float4*)(W + (size_t)bk_s[t] * DIM);
        ((float4*)(outq + (size_t)(tb + t) * DIM))[j] = wr[j];
    }
}

extern "C" void kernel_launch(void* const* d_in, const int* in_sizes, int n_in,
                              void* d_out, int out_size, void* d_ws, size_t ws_size,
                              hipStream_t stream) {
    const float* x = (const float*)d_in[0];
    const float* W = (const float*)d_in[1];
    float* outq   = (float*)d_out;
    float* outidx = outq + (size_t)NTOK * DIM;

    const size_t need = 4096 + (size_t)NCODE * DIM * sizeof(_Float16);
    if (ws_size >= need) {
        float* nw_ws = (float*)d_ws;
        half8* wh_ws = (half8*)((char*)d_ws + 4096);
        prep_kernel<<<NCODE / 8, 256, 0, stream>>>(W, nw_ws, wh_ws);
        vq_kernel<true><<<NTOK / TT, 256, 0, stream>>>(x, W, nw_ws, wh_ws, outq, outidx);
    } else {
        vq_kernel<false><<<NTOK / TT, 256, 0, stream>>>(x, W, nullptr, nullptr, outq, outidx);
    }
}

// Round 2
// 159.333 us; speedup vs baseline: 1.6809x; 1.6809x over previous
//
#include <hip/hip_runtime.h>
#include <float.h>

typedef _Float16 half8  __attribute__((ext_vector_type(8)));
typedef __fp16   fp16x2 __attribute__((ext_vector_type(2)));
typedef float    f32x4  __attribute__((ext_vector_type(4)));

#define NTOK  65536
#define DIM   256
#define NCODE 1024
#define TT    64          // tokens per block; grid = 1024 -> 4 blocks/CU (LDS 38.4 KB)
#define NCT   16          // 16 code-tiles of 64 codes
#define CAP   4096
#define TAU   0.08f
#define BIAS  64.0f       // coarse scores strictly positive -> uint order == float order

__device__ inline half8 pack8(float4 a, float4 b) {
    union { half8 v; fp16x2 h[4]; } u;
    u.h[0] = __builtin_amdgcn_cvt_pkrtz(a.x, a.y);
    u.h[1] = __builtin_amdgcn_cvt_pkrtz(a.z, a.w);
    u.h[2] = __builtin_amdgcn_cvt_pkrtz(b.x, b.y);
    u.h[3] = __builtin_amdgcn_cvt_pkrtz(b.z, b.w);
    return u.v;
}
__device__ inline unsigned umn(unsigned a, unsigned b) { return a < b ? a : b; }
__device__ inline unsigned umx(unsigned a, unsigned b) { return a > b ? a : b; }

// async 16B global->LDS; LDS dest is wave-uniform base + lane*16 by construction
__device__ inline void gload16(const void* g, void* l) {
    __builtin_amdgcn_global_load_lds(
        (__attribute__((address_space(1))) void*)(size_t)g,
        (__attribute__((address_space(3))) void*)l,
        16, 0, 0);
}

// pre-kernel: ||W_k||^2 (fp64->fp32) + W -> f16 chunks (row-major half8)
__global__ __launch_bounds__(256) void prep_kernel(const float* __restrict__ W,
                                                   float* __restrict__ nw_out,
                                                   half8* __restrict__ wh_out) {
    const int tid = threadIdx.x;
    const int k = blockIdx.x * 8 + (tid >> 5);
    const int c = tid & 31;
    const float4* wr = (const float4*)(W + (size_t)k * DIM + c * 8);
    float4 u = wr[0], v = wr[1];
    wh_out[(size_t)k * 32 + c] = pack8(u, v);
    double a = (double)u.x * u.x + (double)u.y * u.y + (double)u.z * u.z + (double)u.w * u.w
             + (double)v.x * v.x + (double)v.y * v.y + (double)v.z * v.z + (double)v.w * v.w;
    #pragma unroll
    for (int m = 1; m <= 16; m <<= 1) a += __shfl_xor(a, m);   // stays within 32-lane group
    if (c == 0) nw_out[k] = (float)a;
}

template <bool PRE>
__global__ __launch_bounds__(256) __attribute__((amdgpu_waves_per_eu(4, 4)))
void vq_kernel(
    const float* __restrict__ x, const float* __restrict__ W,
    const float* __restrict__ nwp, const half8* __restrict__ whp,
    float* __restrict__ outq, float* __restrict__ outidx)
{
    __shared__ _Float16 wtile[64][256];        // 32 KB; aliased as cand list after loop
    __shared__ float nw_s[NCODE];              // 4 KB
    __shared__ float nx_s[TT];
    __shared__ unsigned long long best64[TT];
    __shared__ int cnt_s;
    __shared__ int bk_s[TT];
    unsigned* cand = (unsigned*)&wtile[0][0];

    const int tid = threadIdx.x, tb = blockIdx.x * TT;
    const int wv = tid >> 6, l = tid & 63;
    const int lg = l >> 4;          // k-group (which 8-dim slice of a 32-dim K step)
    const int lr = l & 15;          // row (token) / col (code) within 16

    // ---- nw: load precomputed, or fp64 in-block fallback ----
    if (PRE) {
        ((float4*)nw_s)[tid] = ((const float4*)nwp)[tid];
    } else {
        #pragma unroll
        for (int c = 0; c < 4; ++c) {
            const int k = (tid << 2) + c;
            const float4* wr = (const float4*)(W + (size_t)k * DIM);
            double a0 = 0.0, a1 = 0.0;
            for (int q = 0; q < DIM / 4; ++q) {
                float4 v = wr[q];
                a0 += (double)v.x * v.x + (double)v.y * v.y;
                a1 += (double)v.z * v.z + (double)v.w * v.w;
            }
            nw_s[k] = (float)(a0 + a1);
        }
    }
    if (tid == 0) cnt_s = 0;
    if (tid < TT) best64[tid] = ~0ull;

    // ---- A-fragments (16x16x32: wave owns 16 tokens, 8 K-step frags = 32 VGPR)
    // ---- + FUSED fp64 token norms (no separate x pass) ----
    const int trow = tb + (wv << 4) + lr;
    half8 xa[8];
    {
        double a0 = 0.0, a1 = 0.0;
        #pragma unroll
        for (int s = 0; s < 8; ++s) {
            const float4* p = (const float4*)(x + (size_t)trow * DIM + (s << 5) + (lg << 3));
            float4 u = p[0], v = p[1];
            xa[s] = pack8(u, v);
            a0 += (double)u.x * u.x + (double)u.y * u.y + (double)v.x * v.x + (double)v.y * v.y;
            a1 += (double)u.z * u.z + (double)u.w * u.w + (double)v.z * v.z + (double)v.w * v.w;
        }
        double nx = a0 + a1;
        nx += __shfl_xor(nx, 16);       // combine the 4 k-groups holding this token
        nx += __shfl_xor(nx, 32);
        if (lg == 0) nx_s[(wv << 4) + lr] = (float)nx;
    }

    // staging source chunk swizzle, hoisted out of the ct loop (const per thread)
    unsigned srcoff[8];
    #pragma unroll
    for (int j = 0; j < 8; ++j) {
        const unsigned g = (unsigned)(j * 256 + tid);
        srcoff[j] = (g & ~31u) | ((g & 31u) ^ ((g >> 5) & 31u));
    }

    // per-lane top-2 packed keys per C-reg token slot (4 tokens/lane)
    unsigned b0[4], b1[4];
    #pragma unroll
    for (int j = 0; j < 4; ++j) { b0[j] = 0xFFFFFFFFu; b1[j] = 0xFFFFFFFFu; }

    for (int ct = 0; ct < NCT; ++ct) {
        __syncthreads();   // prior MFMA readers of wtile done
        if (PRE) {
            // async direct-to-LDS; swizzle applied on the GLOBAL chunk index so the
            // LDS destination stays linear. Slot (row n, chunk p) holds source
            // chunk p ^ (n&31) of row n.
            #pragma unroll
            for (int j = 0; j < 8; ++j)
                gload16(whp + (size_t)ct * 2048 + srcoff[j],
                        (_Float16*)&wtile[0][0] + (size_t)(j * 256 + tid) * 8);
        } else {
            const int n = tid >> 2, qq = tid & 3;
            const float4* srcp = (const float4*)(W + (size_t)(ct * 64 + n) * DIM + (qq << 6));
            #pragma unroll
            for (int i = 0; i < 8; ++i) {
                float4 a = srcp[2 * i], b = srcp[2 * i + 1];
                const int c = (qq << 3) + i, p = c ^ (n & 31);
                *(half8*)&wtile[n][p << 3] = pack8(a, b);
            }
        }
        __syncthreads();   // drains vmcnt (global_load_lds) / lgkmcnt

        // 4 independent acc chains (one per 16-code subtile) for MFMA ILP
        f32x4 acc[4];
        #pragma unroll
        for (int st = 0; st < 4; ++st)
            #pragma unroll
            for (int j = 0; j < 4; ++j) acc[st][j] = 0.0f;

        #pragma unroll
        for (int sp = 0; sp < 8; ++sp) {
            const int c = (sp << 2) + lg;       // source chunk for this K step
            #pragma unroll
            for (int st = 0; st < 4; ++st) {
                const int n = (st << 4) + lr;   // code row within tile
                const int p = c ^ (n & 31);     // XOR-deswizzle
                half8 q = *(const half8*)&wtile[n][p << 3];
                acc[st] = __builtin_amdgcn_mfma_f32_16x16x32_f16(xa[sp], q, acc[st], 0, 0, 0);
            }
        }

        // ---- branch-free register top-2 on packed (score,k) keys ----
        #pragma unroll
        for (int st = 0; st < 4; ++st) {
            const int kk = (ct << 6) + (st << 4) + lr;
            const float nwb = nw_s[kk] + BIAS;
            #pragma unroll
            for (int j = 0; j < 4; ++j) {
                const float c = fmaf(acc[st][j], -2.0f, nwb);
                const unsigned u = (__float_as_uint(c) & 0xFFFFFC00u) | (unsigned)kk;
                const unsigned lo = umn(u, b0[j]), hi = umx(u, b0[j]);
                b0[j] = lo;
                b1[j] = umn(hi, b1[j]);
            }
        }
    }

    __syncthreads();   // all MFMA reads of wtile done; alias as cand list

    // ---- per-token cross-lane coarse min (16 lanes, same lg), tau-trigger, append ----
    // each token is covered by exactly one 16-lane group over ALL 1024 codes,
    // so thr is the true global coarse threshold for that token.
    #pragma unroll
    for (int j = 0; j < 4; ++j) {
        unsigned v = b0[j];
        #pragma unroll
        for (int m = 1; m <= 8; m <<= 1) v = umn(v, (unsigned)__shfl_xor((int)v, m));
        const float thr = __uint_as_float(v & 0xFFFFFC00u) + TAU;
        const int t = (wv << 4) + (lg << 2) + j;    // C/D row = (lane>>4)*4 + reg
        if (__uint_as_float(b0[j] & 0xFFFFFC00u) <= thr) {
            int i = atomicAdd(&cnt_s, 1);
            if (i < CAP) cand[i] = ((unsigned)t << 10) | (b0[j] & 1023u);
        }
        if (__uint_as_float(b1[j] & 0xFFFFFC00u) <= thr) {
            int i = atomicAdd(&cnt_s, 1);
            if (i < CAP) cand[i] = ((unsigned)t << 10) | (b1[j] & 1023u);
        }
    }
    __syncthreads();

    // ---- wave-cooperative exact fp32 rescore; lexicographic (dv,k) atomicMin ----
    const int nc = min(cnt_s, CAP);
    for (int c = wv; c < nc; c += 4) {
        const unsigned en = cand[c];
        const int t = en >> 10, k = en & 1023;
        float4 xv = ((const float4*)(x + (size_t)(tb + t) * DIM))[l];
        float4 wr = ((const float4*)(W + (size_t)k * DIM))[l];
        float s = fmaf(xv.x, wr.x, fmaf(xv.y, wr.y, fmaf(xv.z, wr.z, xv.w * wr.w)));
        #pragma unroll
        for (int m = 1; m <= 32; m <<= 1) s += __shfl_xor(s, m);
        const float dv = (nx_s[t] + nw_s[k]) - 2.0f * s;
        if (l == 0) {
            unsigned long long key = ((unsigned long long)__float_as_uint(dv) << 32) | (unsigned)k;
            atomicMin(&best64[t], key);
        }
    }
    __syncthreads();

    if (tid < TT) {
        const int bk = (int)(best64[tid] & 1023u);
        bk_s[tid] = bk;
        outidx[tb + tid] = (float)bk;   // whole d_out read back as fp32
    }
    __syncthreads();

    // ---- gather codebook rows -> quantized output (coalesced float4) ----
    for (int i = tid; i < TT * (DIM / 4); i += 256) {
        const int t = i >> 6, j = i & 63;
        const float4* wr = (const float4*)(W + (size_t)bk_s[t] * DIM);
        ((float4*)(outq + (size_t)(tb + t) * DIM))[j] = wr[j];
    }
}

extern "C" void kernel_launch(void* const* d_in, const int* in_sizes, int n_in,
                              void* d_out, int out_size, void* d_ws, size_t ws_size,
                              hipStream_t stream) {
    const float* x = (const float*)d_in[0];
    const float* W = (const float*)d_in[1];
    float* outq   = (float*)d_out;
    float* outidx = outq + (size_t)NTOK * DIM;

    const size_t need = 4096 + (size_t)NCODE * DIM * sizeof(_Float16);
    if (ws_size >= need) {
        float* nw_ws = (float*)d_ws;
        half8* wh_ws = (half8*)((char*)d_ws + 4096);
        prep_kernel<<<NCODE / 8, 256, 0, stream>>>(W, nw_ws, wh_ws);
        vq_kernel<true><<<NTOK / TT, 256, 0, stream>>>(x, W, nw_ws, wh_ws, outq, outidx);
    } else {
        vq_kernel<false><<<NTOK / TT, 256, 0, stream>>>(x, W, nullptr, nullptr, outq, outidx);
    }
}